// Round 9
// baseline (394.578 us; speedup 1.0000x reference)
//
#include <hip/hip_runtime.h>
#include <hip/hip_bf16.h>
#include <stdint.h>

// Problem constants
#define B_    16
#define N_    256
#define HID_  512
#define H_    8
#define DK_   64
#define FEAT_ 8
#define MLPH_ 64
#define LAM_  0.1f
#define SCALE_ 0.125f   // DK^-0.5

typedef short bf16x8 __attribute__((ext_vector_type(8)));
typedef float f32x4  __attribute__((ext_vector_type(4)));

union U8 { uint4 u; bf16x8 h; ushort s[8]; };

__device__ __forceinline__ uint16_t f32_to_bf16(float x) {
    uint32_t u = __float_as_uint(x);
    u += 0x7fffu + ((u >> 16) & 1u);      // RNE (no NaN/Inf in this data)
    return (uint16_t)(u >> 16);
}
__device__ __forceinline__ float bf16_to_f32(uint16_t v) {
    return __uint_as_float(((uint32_t)v) << 16);
}
__device__ __forceinline__ uint32_t pk_bf16(float lo, float hi) {
    float2 xy; xy.x = lo; xy.y = hi;
    __hip_bfloat162 b2 = __float22bfloat162_rn(xy);   // HW packed cvt on gfx950
    return *(uint32_t*)&b2;                            // .x in low 16 bits
}
// LDS-only fence: compiler barrier + drain LDS queue. Does NOT wait vmcnt, so
// global stores (mlpb) stay in flight. DS ops of one wave complete in order;
// the hazard R7 fixed was compiler reordering, which the memory clobber blocks.
#define LDS_FENCE() asm volatile("s_waitcnt lgkmcnt(0)" ::: "memory")

// ---------- K1: QKV projection, bf16 MFMA GEMM (unchanged) ----------
__global__ __launch_bounds__(256, 4) void proj_kernel(
    const float* __restrict__ q, const float* __restrict__ k, const float* __restrict__ v,
    const float* __restrict__ Wq, const float* __restrict__ bq,
    const float* __restrict__ Wk, const float* __restrict__ bk,
    const float* __restrict__ Wv, const float* __restrict__ bv,
    ushort* __restrict__ qh, ushort* __restrict__ kh, ushort* __restrict__ vh)
{
    int z = blockIdx.z;
    const float* X    = (z == 0) ? q  : (z == 1) ? k  : v;
    const float* W    = (z == 0) ? Wq : (z == 1) ? Wk : Wv;
    const float* bias = (z == 0) ? bq : (z == 1) ? bk : bv;
    ushort* out       = (z == 0) ? qh : (z == 1) ? kh : vh;
    float scale       = (z == 0) ? SCALE_ : 1.0f;

    int m0 = blockIdx.x * 64;
    int h  = blockIdx.y;
    int c0 = h * 64;

    __shared__ __align__(16) ushort Xs[64 * 40];
    __shared__ __align__(16) ushort Ws[64 * 40];

    int t = threadIdx.x;
    int wave = t >> 6, lane = t & 63;
    int l15 = lane & 15, qd = lane >> 4;

    f32x4 acc[4] = {};

    for (int k0 = 0; k0 < HID_; k0 += 32) {
        __syncthreads();
        #pragma unroll
        for (int u = t; u < 512; u += 256) {
            int r = u >> 3, c4 = (u & 7) * 4;
            float4 xv = *(const float4*)&X[(m0 + r) * HID_ + k0 + c4];
            ushort4 o;
            o.x = f32_to_bf16(xv.x); o.y = f32_to_bf16(xv.y);
            o.z = f32_to_bf16(xv.z); o.w = f32_to_bf16(xv.w);
            *(ushort4*)&Xs[r * 40 + c4] = o;
        }
        {
            int kr = t & 15, nq = t >> 4;
            float4 w0 = *(const float4*)&W[(k0 + 2 * kr) * HID_ + c0 + nq * 4];
            float4 w1 = *(const float4*)&W[(k0 + 2 * kr + 1) * HID_ + c0 + nq * 4];
            const float* a0 = &w0.x; const float* a1 = &w1.x;
            #pragma unroll
            for (int i = 0; i < 4; i++) {
                uint32_t pk = (uint32_t)f32_to_bf16(a0[i]) | ((uint32_t)f32_to_bf16(a1[i]) << 16);
                *(uint32_t*)&Ws[(nq * 4 + i) * 40 + 2 * kr] = pk;
            }
        }
        __syncthreads();
        bf16x8 af = *(const bf16x8*)&Xs[(wave * 16 + l15) * 40 + qd * 8];
        #pragma unroll
        for (int nt = 0; nt < 4; nt++) {
            bf16x8 bf = *(const bf16x8*)&Ws[(nt * 16 + l15) * 40 + qd * 8];
            acc[nt] = __builtin_amdgcn_mfma_f32_16x16x32_bf16(af, bf, acc[nt], 0, 0, 0);
        }
    }

    #pragma unroll
    for (int nt = 0; nt < 4; nt++) {
        float bb = bias[c0 + nt * 16 + l15];
        #pragma unroll
        for (int r = 0; r < 4; r++) {
            int m = m0 + wave * 16 + qd * 4 + r;
            int b_ = m >> 8, n_ = m & 255;
            float val = (acc[nt][r] + bb) * scale;
            out[(((b_ * H_ + h) * N_) + n_) * DK_ + nt * 16 + l15] = f32_to_bf16(val);
        }
    }
}

// ---------- K2: one-block prep — B-fragments in MFMA frag order (global) ------
// bfrag1[nt*64+lane]: GEMM1 B, lane=(l15=n-within-tile, qd), k=qd*8+u.
//   B1[k][n]: k0..7=Wc_s, 8..15=Wb_s (n<64); 16..23=Wc_o, 24..31=Wb_o (n>=64).
// bfrag2[ks*64+lane]: GEMM2 B under pi-permutation c=((k2&7)<<4)|(k2>>3), LAM-scaled.
__global__ void prep_frags(const float* __restrict__ fsW1, const float* __restrict__ foW1,
                           const float* __restrict__ fsW2, const float* __restrict__ foW2,
                           uint4* __restrict__ bfrag1, uint4* __restrict__ bfrag2)
{
    int t = threadIdx.x;
    #pragma unroll
    for (int e = t; e < 512; e += 256) {
        int nt = e >> 6, lane = e & 63, l15 = lane & 15, qd = lane >> 4;
        int n = nt * 16 + l15;
        ushort vals[8];
        #pragma unroll
        for (int u = 0; u < 8; u++) {
            float x = 0.f;
            if (n < 64) {
                if (qd == 0) x = fsW1[(16 + u) * 64 + n];
                else if (qd == 1) x = fsW1[(8 + u) * 64 + n];
            } else {
                int n2 = n - 64;
                if (qd == 2) x = foW1[(16 + u) * 64 + n2];
                else if (qd == 3) x = foW1[(8 + u) * 64 + n2];
            }
            vals[u] = f32_to_bf16(x);
        }
        uint4 pk;
        pk.x = (uint32_t)vals[0] | ((uint32_t)vals[1] << 16);
        pk.y = (uint32_t)vals[2] | ((uint32_t)vals[3] << 16);
        pk.z = (uint32_t)vals[4] | ((uint32_t)vals[5] << 16);
        pk.w = (uint32_t)vals[6] | ((uint32_t)vals[7] << 16);
        bfrag1[e] = pk;
    }
    {
        int e = t;
        int ks = e >> 6, lane = e & 63, l15 = lane & 15, qd = lane >> 4;
        ushort vals[8];
        #pragma unroll
        for (int u = 0; u < 8; u++) {
            float x = 0.f;
            if (l15 < 8) {
                int k2 = ks * 32 + qd * 8 + u;
                int c = ((k2 & 7) << 4) | (k2 >> 3);
                x = LAM_ * ((c < 64) ? fsW2[c * 8 + l15] : foW2[(c - 64) * 8 + l15]);
            }
            vals[u] = f32_to_bf16(x);
        }
        uint4 pk;
        pk.x = (uint32_t)vals[0] | ((uint32_t)vals[1] << 16);
        pk.y = (uint32_t)vals[2] | ((uint32_t)vals[3] << 16);
        pk.z = (uint32_t)vals[4] | ((uint32_t)vals[5] << 16);
        pk.w = (uint32_t)vals[6] | ((uint32_t)vals[7] << 16);
        bfrag2[e] = pk;
    }
}

// ---------- K3: pair-MLP via MFMA -> mlpb = bf16(LAM*(mlp_s+mlp_o+b2)) ----------
// R9: B-frags from global (no LDS weight staging -> 19.9 KB LDS, 8 blocks/CU);
// LDS-only lgkmcnt fences (mlpb stores stay in flight); his folded into MFMA C.
#define HSTRIDE 136
__global__ __launch_bounds__(256, 7) void pair_bias_mfma(
    const float* __restrict__ sf, const float* __restrict__ of,
    const float* __restrict__ fsW1, const float* __restrict__ fsb1,
    const float* __restrict__ foW1, const float* __restrict__ fob1,
    const float* __restrict__ fsb2, const float* __restrict__ fob2,
    const uint4* __restrict__ bfrag1, const uint4* __restrict__ bfrag2,
    ushort* __restrict__ mlpb)
{
    __shared__ __align__(16) ushort hbuf[4][16 * HSTRIDE];  // per-wave h (17,408 B)
    __shared__ float hisbuf[128];
    __shared__ __align__(4) ushort tbuf[4][8 * 16];

    int i = blockIdx.x, b = blockIdx.y;
    int t = threadIdx.x;
    int wave = t >> 6, lane = t & 63;
    int l15 = lane & 15, qd = lane >> 4;

    // in-block his: hisbuf[c] = b1[c] + feat_i . W1a  (c<64: s-set, else o-set)
    if (t < 128) {
        int set = t >> 6, kk = t & 63;
        const float* W1 = set ? foW1 : fsW1;
        const float* fi = (set ? of : sf) + (b * N_ + i) * FEAT_;
        float a = (set ? fob1 : fsb1)[kk];
        #pragma unroll
        for (int f = 0; f < FEAT_; f++) a += fi[f] * W1[f * 64 + kk];
        hisbuf[t] = a;
    }

    // B-fragments: coalesced global loads in frag order (L2-resident after block 0)
    bf16x8 Bf1[8], Bf2[4];
    #pragma unroll
    for (int nt = 0; nt < 8; nt++) { U8 u; u.u = bfrag1[nt * 64 + lane]; Bf1[nt] = u.h; }
    #pragma unroll
    for (int ks = 0; ks < 4; ks++) { U8 u; u.u = bfrag2[ks * 64 + lane]; Bf2[ks] = u.h; }

    const float* fsr = sf + (b * N_ + i) * FEAT_;
    const float* forr = of + (b * N_ + i) * FEAT_;
    float fsi[8], foi[8];
    #pragma unroll
    for (int u = 0; u < 8; u++) { fsi[u] = fsr[u]; foi[u] = forr[u]; }
    float b2l = LAM_ * (fsb2[l15 & 7] + fob2[l15 & 7]);

    __syncthreads();   // hisbuf ready (cross-wave)

    float hv[8];
    #pragma unroll
    for (int nt = 0; nt < 8; nt++) hv[nt] = hisbuf[nt * 16 + l15];

    ushort* hb = hbuf[wave];
    #pragma unroll
    for (int qt = 0; qt < 4; qt++) {
        int j0 = (wave * 4 + qt) * 16;
        int j = j0 + l15;

        // ---- A-frag: qd0 |ds|, qd1 fs_j, qd2 |do|, qd3 fo_j ----
        const float* fr = ((qd < 2) ? sf : of) + (b * N_ + j) * FEAT_;
        float4 f0 = *(const float4*)&fr[0];
        float4 f1 = *(const float4*)&fr[4];
        float vals[8] = {f0.x, f0.y, f0.z, f0.w, f1.x, f1.y, f1.z, f1.w};
        if ((qd & 1) == 0) {
            const float* fi = (qd < 2) ? fsi : foi;
            #pragma unroll
            for (int u = 0; u < 8; u++) vals[u] = fabsf(vals[u] - fi[u]);
        }
        U8 au;
        #pragma unroll
        for (int p = 0; p < 4; p++)
            ((uint32_t*)&au)[p] = pk_bf16(vals[2 * p], vals[2 * p + 1]);
        bf16x8 af = au.h;

        // ---- GEMM1 with his in C-operand ----
        f32x4 S1[8];
        #pragma unroll
        for (int nt = 0; nt < 8; nt++) {
            f32x4 c0 = {hv[nt], hv[nt], hv[nt], hv[nt]};
            S1[nt] = __builtin_amdgcn_mfma_f32_16x16x32_bf16(af, Bf1[nt], c0, 0, 0, 0);
        }

        // ---- relu + packed cvt + one b128 write per row (pi layout) ----
        #pragma unroll
        for (int r = 0; r < 4; r++) {
            uint4 w;
            w.x = pk_bf16(fmaxf(S1[0][r], 0.f), fmaxf(S1[1][r], 0.f));
            w.y = pk_bf16(fmaxf(S1[2][r], 0.f), fmaxf(S1[3][r], 0.f));
            w.z = pk_bf16(fmaxf(S1[4][r], 0.f), fmaxf(S1[5][r], 0.f));
            w.w = pk_bf16(fmaxf(S1[6][r], 0.f), fmaxf(S1[7][r], 0.f));
            *(uint4*)&hb[(qd * 4 + r) * HSTRIDE + l15 * 8] = w;
        }
        LDS_FENCE();   // LDS-only: h writes ordered before GEMM2 reads

        // ---- GEMM2: K=128 (pi-consistent), C-init = LAM*b2 ----
        f32x4 S2 = {b2l, b2l, b2l, b2l};
        #pragma unroll
        for (int ks = 0; ks < 4; ks++) {
            bf16x8 a2 = *(const bf16x8*)&hb[l15 * HSTRIDE + ks * 32 + qd * 8];
            S2 = __builtin_amdgcn_mfma_f32_16x16x32_bf16(a2, Bf2[ks], S2, 0, 0, 0);
        }

        // ---- transpose 16j x 8h via tbuf (per-wave) ----
        if (l15 < 8) {
            #pragma unroll
            for (int r = 0; r < 4; r++)
                tbuf[wave][l15 * 16 + qd * 4 + r] = f32_to_bf16(S2[r]);
        }
        LDS_FENCE();   // LDS-only: tbuf writes ordered before reads

        {
            int h2 = lane >> 3, jp = lane & 7;
            uint32_t lo = tbuf[wave][h2 * 16 + jp * 2];
            uint32_t hi = tbuf[wave][h2 * 16 + jp * 2 + 1];
            uint32_t pk = lo | (hi << 16);
            *(uint32_t*)&mlpb[(((size_t)(b * H_ + h2) * N_ + i) * N_) + j0 + jp * 2] = pk;
        }
    }
}

// ---------- K4: MFMA attention (ctx bf16) (unchanged from R8) ----------
__global__ __launch_bounds__(256, 2) void attn_kernel(
    const ushort* __restrict__ qh, const ushort* __restrict__ kh,
    const ushort* __restrict__ vh, const float* __restrict__ tree,
    const ushort* __restrict__ mlpb, ushort* __restrict__ ctxb)
{
    __shared__ __align__(16) ushort bufKP[256 * 72];
    __shared__ __align__(16) ushort bufV[64 * 264];

    int blk = blockIdx.x;
    int bh = blk >> 2;
    int quarter = blk & 3;

    int t = threadIdx.x;
    int wave = t >> 6, lane = t & 63;
    int l15 = lane & 15, qd = lane >> 4;
    int i0w = quarter * 64 + wave * 16;

    const ushort* khb = kh + (size_t)bh * N_ * DK_;
    const ushort* vhb = vh + (size_t)bh * N_ * DK_;

    #pragma unroll
    for (int u = t; u < 2048; u += 256) {
        int j = u >> 3, seg = (u & 7) * 8;
        uint4 kv = *(const uint4*)&khb[j * DK_ + seg];
        *(uint4*)&bufKP[j * 72 + seg] = kv;
    }
    #pragma unroll
    for (int u = t; u < 1024; u += 256) {
        int rp = u & 127, d0 = (u >> 7) * 8;
        U8 v0, v1;
        v0.u = *(const uint4*)&vhb[(2 * rp) * DK_ + d0];
        v1.u = *(const uint4*)&vhb[(2 * rp + 1) * DK_ + d0];
        #pragma unroll
        for (int jj = 0; jj < 8; jj++) {
            uint32_t pk = (uint32_t)v0.s[jj] | ((uint32_t)v1.s[jj] << 16);
            *(uint32_t*)&bufV[(d0 + jj) * 264 + 2 * rp] = pk;
        }
    }
    __syncthreads();

    bf16x8 a0, a1;
    {
        size_t qb = ((size_t)bh * N_ + i0w + l15) * DK_;
        U8 t0, t1;
        t0.u = *(const uint4*)&qh[qb + qd * 8];
        t1.u = *(const uint4*)&qh[qb + 32 + qd * 8];
        a0 = t0.h; a1 = t1.h;
    }
    f32x4 S[16];
    #pragma unroll
    for (int nt = 0; nt < 16; nt++) {
        f32x4 acc = {};
        bf16x8 b0 = *(const bf16x8*)&bufKP[(nt * 16 + l15) * 72 + qd * 8];
        bf16x8 b1 = *(const bf16x8*)&bufKP[(nt * 16 + l15) * 72 + 32 + qd * 8];
        acc = __builtin_amdgcn_mfma_f32_16x16x32_bf16(a0, b0, acc, 0, 0, 0);
        acc = __builtin_amdgcn_mfma_f32_16x16x32_bf16(a1, b1, acc, 0, 0, 0);
        S[nt] = acc;
    }

    {
        size_t base = ((size_t)bh * N_ + i0w + qd * 4) * N_ + l15;
        const float*  tr = tree + base;
        const ushort* mb = mlpb + base;
        #pragma unroll
        for (int nt = 0; nt < 16; nt++)
            #pragma unroll
            for (int r = 0; r < 4; r++)
                S[nt][r] += tr[(size_t)r * N_ + nt * 16] + bf16_to_f32(mb[(size_t)r * N_ + nt * 16]);
    }

    float mx[4], sm[4];
    #pragma unroll
    for (int r = 0; r < 4; r++) mx[r] = -1e30f;
    #pragma unroll
    for (int nt = 0; nt < 16; nt++)
        #pragma unroll
        for (int r = 0; r < 4; r++) mx[r] = fmaxf(mx[r], S[nt][r]);
    #pragma unroll
    for (int r = 0; r < 4; r++) {
        #pragma unroll
        for (int m = 1; m <= 8; m <<= 1) mx[r] = fmaxf(mx[r], __shfl_xor(mx[r], m));
    }
    #pragma unroll
    for (int r = 0; r < 4; r++) sm[r] = 0.f;
    #pragma unroll
    for (int nt = 0; nt < 16; nt++)
        #pragma unroll
        for (int r = 0; r < 4; r++) {
            float e = __expf(S[nt][r] - mx[r]);
            S[nt][r] = e;
            sm[r] += e;
        }
    #pragma unroll
    for (int r = 0; r < 4; r++) {
        #pragma unroll
        for (int m = 1; m <= 8; m <<= 1) sm[r] += __shfl_xor(sm[r], m);
        sm[r] = 1.0f / sm[r];
    }

    __syncthreads();

    {
        uint32_t* Pw = (uint32_t*)&bufKP[wave * 16 * 264];
        #pragma unroll
        for (int nt = 0; nt < 16; nt++)
            #pragma unroll
            for (int r = 0; r < 4; r++) {
                float p = S[nt][r] * sm[r];
                float po = __shfl_xor(p, 1);
                uint32_t pk = (uint32_t)f32_to_bf16(p) | ((uint32_t)f32_to_bf16(po) << 16);
                if ((lane & 1) == 0)
                    Pw[(qd * 4 + r) * 132 + nt * 8 + (l15 >> 1)] = pk;
            }
    }
    __syncthreads();   // P writes complete before PV reads

    const ushort* Pw = &bufKP[wave * 16 * 264];
    f32x4 O[4] = {};
    #pragma unroll
    for (int ks = 0; ks < 8; ks++) {
        int j0 = ks * 32;
        bf16x8 pa = *(const bf16x8*)&Pw[l15 * 264 + j0 + qd * 8];
        #pragma unroll
        for (int ntd = 0; ntd < 4; ntd++) {
            bf16x8 vb = *(const bf16x8*)&bufV[(ntd * 16 + l15) * 264 + j0 + qd * 8];
            O[ntd] = __builtin_amdgcn_mfma_f32_16x16x32_bf16(pa, vb, O[ntd], 0, 0, 0);
        }
    }

    #pragma unroll
    for (int ntd = 0; ntd < 4; ntd++)
        #pragma unroll
        for (int r = 0; r < 4; r++)
            ctxb[((size_t)bh * N_ + i0w + qd * 4 + r) * DK_ + ntd * 16 + l15] =
                f32_to_bf16(O[ntd][r]);
}

// ---------- K5: output projection, bf16 MFMA (unchanged from R8) ----------
__global__ __launch_bounds__(256, 4) void outproj_kernel(
    const ushort* __restrict__ ctxb, const float* __restrict__ Wo,
    const float* __restrict__ bo, float* __restrict__ out)
{
    int m0 = blockIdx.x * 64;
    int c0 = blockIdx.y * 64;

    __shared__ __align__(16) ushort Xs[64 * 40];
    __shared__ __align__(16) ushort Ws[64 * 40];

    int t = threadIdx.x;
    int wave = t >> 6, lane = t & 63;
    int l15 = lane & 15, qd = lane >> 4;

    f32x4 acc[4] = {};

    for (int k0 = 0; k0 < HID_; k0 += 32) {
        __syncthreads();
        {
            int r = t >> 2, s8 = (t & 3) * 8;
            int m = m0 + r, b_ = m >> 8, n_ = m & 255;
            uint4 xv = *(const uint4*)&ctxb[(((b_ * H_ + (k0 >> 6)) * N_) + n_) * DK_ + (k0 & 63) + s8];
            *(uint4*)&Xs[r * 40 + s8] = xv;
        }
        {
            int kr = t & 15, nq = t >> 4;
            float4 w0 = *(const float4*)&Wo[(k0 + 2 * kr) * HID_ + c0 + nq * 4];
            float4 w1 = *(const float4*)&Wo[(k0 + 2 * kr + 1) * HID_ + c0 + nq * 4];
            const float* a0 = &w0.x; const float* a1 = &w1.x;
            #pragma unroll
            for (int i = 0; i < 4; i++) {
                uint32_t pk = (uint32_t)f32_to_bf16(a0[i]) | ((uint32_t)f32_to_bf16(a1[i]) << 16);
                *(uint32_t*)&Ws[(nq * 4 + i) * 40 + 2 * kr] = pk;
            }
        }
        __syncthreads();
        bf16x8 af = *(const bf16x8*)&Xs[(wave * 16 + l15) * 40 + qd * 8];
        #pragma unroll
        for (int nt = 0; nt < 4; nt++) {
            bf16x8 bf = *(const bf16x8*)&Ws[(nt * 16 + l15) * 40 + qd * 8];
            acc[nt] = __builtin_amdgcn_mfma_f32_16x16x32_bf16(af, bf, acc[nt], 0, 0, 0);
        }
    }

    #pragma unroll
    for (int nt = 0; nt < 4; nt++) {
        float bb = bo[c0 + nt * 16 + l15];
        #pragma unroll
        for (int r = 0; r < 4; r++) {
            int m = m0 + wave * 16 + qd * 4 + r;
            out[m * HID_ + c0 + nt * 16 + l15] = acc[nt][r] + bb;
        }
    }
}

// ---------- launch ----------
extern "C" void kernel_launch(void* const* d_in, const int* in_sizes, int n_in,
                              void* d_out, int out_size, void* d_ws, size_t ws_size,
                              hipStream_t stream)
{
    const float* q    = (const float*)d_in[0];
    const float* k    = (const float*)d_in[1];
    const float* v    = (const float*)d_in[2];
    const float* tree = (const float*)d_in[3];
    const float* sf   = (const float*)d_in[4];
    const float* of   = (const float*)d_in[5];
    const float* Wq   = (const float*)d_in[6];
    const float* bq   = (const float*)d_in[7];
    const float* Wk   = (const float*)d_in[8];
    const float* bk   = (const float*)d_in[9];
    const float* Wv   = (const float*)d_in[10];
    const float* bv   = (const float*)d_in[11];
    const float* Wo   = (const float*)d_in[12];
    const float* bo   = (const float*)d_in[13];
    const float* fsW1 = (const float*)d_in[14];
    const float* fsb1 = (const float*)d_in[15];
    const float* fsW2 = (const float*)d_in[16];
    const float* fsb2 = (const float*)d_in[17];
    const float* foW1 = (const float*)d_in[18];
    const float* fob1 = (const float*)d_in[19];
    const float* foW2 = (const float*)d_in[20];
    const float* fob2 = (const float*)d_in[21];

    char* ws = (char*)d_ws;
    ushort* qh     = (ushort*)(ws + 0);            // 4,194,304
    ushort* kh     = (ushort*)(ws + 4194304);      // 4,194,304
    ushort* vh     = (ushort*)(ws + 8388608);      // 4,194,304
    ushort* ctxb   = (ushort*)(ws + 12582912);     // 4,194,304 (bf16)
    uint4*  bfrag1 = (uint4*)(ws + 16777216);      //     8,192
    uint4*  bfrag2 = (uint4*)(ws + 16785408);      //     4,096
    ushort* mlpb   = (ushort*)(ws + 23080960);     // 16,777,216

    proj_kernel<<<dim3(64, 8, 3), 256, 0, stream>>>(q, k, v, Wq, bq, Wk, bk, Wv, bv, qh, kh, vh);
    prep_frags<<<1, 256, 0, stream>>>(fsW1, foW1, fsW2, foW2, bfrag1, bfrag2);
    pair_bias_mfma<<<dim3(N_, B_), 256, 0, stream>>>(sf, of, fsW1, fsb1, foW1, fob1,
                                                     fsb2, fob2, bfrag1, bfrag2, mlpb);
    attn_kernel<<<512, 256, 0, stream>>>(qh, kh, vh, tree, mlpb, ctxb);
    outproj_kernel<<<dim3(64, 8), 256, 0, stream>>>(ctxb, Wo, bo, (float*)d_out);
}

// Round 10
// 233.945 us; speedup vs baseline: 1.6866x; 1.6866x over previous
//
#include <hip/hip_runtime.h>
#include <hip/hip_bf16.h>
#include <stdint.h>

// Problem constants
#define B_    16
#define N_    256
#define HID_  512
#define H_    8
#define DK_   64
#define FEAT_ 8
#define MLPH_ 64
#define LAM_  0.1f
#define SCALE_ 0.125f   // DK^-0.5

typedef short bf16x8 __attribute__((ext_vector_type(8)));
typedef float f32x4  __attribute__((ext_vector_type(4)));

union U8 { uint4 u; bf16x8 h; ushort s[8]; };

__device__ __forceinline__ uint16_t f32_to_bf16(float x) {
    uint32_t u = __float_as_uint(x);
    u += 0x7fffu + ((u >> 16) & 1u);      // RNE (no NaN/Inf in this data)
    return (uint16_t)(u >> 16);
}
__device__ __forceinline__ float bf16_to_f32(uint16_t v) {
    return __uint_as_float(((uint32_t)v) << 16);
}
__device__ __forceinline__ uint32_t pk_bf16(float lo, float hi) {
    float2 xy; xy.x = lo; xy.y = hi;
    __hip_bfloat162 b2 = __float22bfloat162_rn(xy);   // HW packed cvt on gfx950
    return *(uint32_t*)&b2;                            // .x in low 16 bits
}
// LDS-only fence: compiler barrier + drain LDS queue. Does NOT wait vmcnt, so
// global stores (mlpb) stay in flight.
#define LDS_FENCE() asm volatile("s_waitcnt lgkmcnt(0)" ::: "memory")

// ---------- K1: QKV projection, bf16 MFMA GEMM (unchanged) ----------
__global__ __launch_bounds__(256, 4) void proj_kernel(
    const float* __restrict__ q, const float* __restrict__ k, const float* __restrict__ v,
    const float* __restrict__ Wq, const float* __restrict__ bq,
    const float* __restrict__ Wk, const float* __restrict__ bk,
    const float* __restrict__ Wv, const float* __restrict__ bv,
    ushort* __restrict__ qh, ushort* __restrict__ kh, ushort* __restrict__ vh)
{
    int z = blockIdx.z;
    const float* X    = (z == 0) ? q  : (z == 1) ? k  : v;
    const float* W    = (z == 0) ? Wq : (z == 1) ? Wk : Wv;
    const float* bias = (z == 0) ? bq : (z == 1) ? bk : bv;
    ushort* out       = (z == 0) ? qh : (z == 1) ? kh : vh;
    float scale       = (z == 0) ? SCALE_ : 1.0f;

    int m0 = blockIdx.x * 64;
    int h  = blockIdx.y;
    int c0 = h * 64;

    __shared__ __align__(16) ushort Xs[64 * 40];
    __shared__ __align__(16) ushort Ws[64 * 40];

    int t = threadIdx.x;
    int wave = t >> 6, lane = t & 63;
    int l15 = lane & 15, qd = lane >> 4;

    f32x4 acc[4] = {};

    for (int k0 = 0; k0 < HID_; k0 += 32) {
        __syncthreads();
        #pragma unroll
        for (int u = t; u < 512; u += 256) {
            int r = u >> 3, c4 = (u & 7) * 4;
            float4 xv = *(const float4*)&X[(m0 + r) * HID_ + k0 + c4];
            ushort4 o;
            o.x = f32_to_bf16(xv.x); o.y = f32_to_bf16(xv.y);
            o.z = f32_to_bf16(xv.z); o.w = f32_to_bf16(xv.w);
            *(ushort4*)&Xs[r * 40 + c4] = o;
        }
        {
            int kr = t & 15, nq = t >> 4;
            float4 w0 = *(const float4*)&W[(k0 + 2 * kr) * HID_ + c0 + nq * 4];
            float4 w1 = *(const float4*)&W[(k0 + 2 * kr + 1) * HID_ + c0 + nq * 4];
            const float* a0 = &w0.x; const float* a1 = &w1.x;
            #pragma unroll
            for (int i = 0; i < 4; i++) {
                uint32_t pk = (uint32_t)f32_to_bf16(a0[i]) | ((uint32_t)f32_to_bf16(a1[i]) << 16);
                *(uint32_t*)&Ws[(nq * 4 + i) * 40 + 2 * kr] = pk;
            }
        }
        __syncthreads();
        bf16x8 af = *(const bf16x8*)&Xs[(wave * 16 + l15) * 40 + qd * 8];
        #pragma unroll
        for (int nt = 0; nt < 4; nt++) {
            bf16x8 bf = *(const bf16x8*)&Ws[(nt * 16 + l15) * 40 + qd * 8];
            acc[nt] = __builtin_amdgcn_mfma_f32_16x16x32_bf16(af, bf, acc[nt], 0, 0, 0);
        }
    }

    #pragma unroll
    for (int nt = 0; nt < 4; nt++) {
        float bb = bias[c0 + nt * 16 + l15];
        #pragma unroll
        for (int r = 0; r < 4; r++) {
            int m = m0 + wave * 16 + qd * 4 + r;
            int b_ = m >> 8, n_ = m & 255;
            float val = (acc[nt][r] + bb) * scale;
            out[(((b_ * H_ + h) * N_) + n_) * DK_ + nt * 16 + l15] = f32_to_bf16(val);
        }
    }
}

// ---------- K2: one-block prep — B-fragments in MFMA frag order (global) ------
__global__ void prep_frags(const float* __restrict__ fsW1, const float* __restrict__ foW1,
                           const float* __restrict__ fsW2, const float* __restrict__ foW2,
                           uint4* __restrict__ bfrag1, uint4* __restrict__ bfrag2)
{
    int t = threadIdx.x;
    #pragma unroll
    for (int e = t; e < 512; e += 256) {
        int nt = e >> 6, lane = e & 63, l15 = lane & 15, qd = lane >> 4;
        int n = nt * 16 + l15;
        ushort vals[8];
        #pragma unroll
        for (int u = 0; u < 8; u++) {
            float x = 0.f;
            if (n < 64) {
                if (qd == 0) x = fsW1[(16 + u) * 64 + n];
                else if (qd == 1) x = fsW1[(8 + u) * 64 + n];
            } else {
                int n2 = n - 64;
                if (qd == 2) x = foW1[(16 + u) * 64 + n2];
                else if (qd == 3) x = foW1[(8 + u) * 64 + n2];
            }
            vals[u] = f32_to_bf16(x);
        }
        uint4 pk;
        pk.x = (uint32_t)vals[0] | ((uint32_t)vals[1] << 16);
        pk.y = (uint32_t)vals[2] | ((uint32_t)vals[3] << 16);
        pk.z = (uint32_t)vals[4] | ((uint32_t)vals[5] << 16);
        pk.w = (uint32_t)vals[6] | ((uint32_t)vals[7] << 16);
        bfrag1[e] = pk;
    }
    {
        int e = t;
        int ks = e >> 6, lane = e & 63, l15 = lane & 15, qd = lane >> 4;
        ushort vals[8];
        #pragma unroll
        for (int u = 0; u < 8; u++) {
            float x = 0.f;
            if (l15 < 8) {
                int k2 = ks * 32 + qd * 8 + u;
                int c = ((k2 & 7) << 4) | (k2 >> 3);
                x = LAM_ * ((c < 64) ? fsW2[c * 8 + l15] : foW2[(c - 64) * 8 + l15]);
            }
            vals[u] = f32_to_bf16(x);
        }
        uint4 pk;
        pk.x = (uint32_t)vals[0] | ((uint32_t)vals[1] << 16);
        pk.y = (uint32_t)vals[2] | ((uint32_t)vals[3] << 16);
        pk.z = (uint32_t)vals[4] | ((uint32_t)vals[5] << 16);
        pk.w = (uint32_t)vals[6] | ((uint32_t)vals[7] << 16);
        bfrag2[e] = pk;
    }
}

// ---------- K3: pair-MLP via MFMA -> mlpb = bf16(LAM*(mlp_s+mlp_o+b2)) ----------
// R10: same as R9 but __launch_bounds__(256, 4) — the (256,7) VGPR cap (73) was
// below the kernel's natural ~70-80 reg footprint; allocator fell to 36 VGPRs
// with massive scratch spills (800 MB HBM traffic/dispatch, 200 µs). Cap 128.
#define HSTRIDE 136
__global__ __launch_bounds__(256, 4) void pair_bias_mfma(
    const float* __restrict__ sf, const float* __restrict__ of,
    const float* __restrict__ fsW1, const float* __restrict__ fsb1,
    const float* __restrict__ foW1, const float* __restrict__ fob1,
    const float* __restrict__ fsb2, const float* __restrict__ fob2,
    const uint4* __restrict__ bfrag1, const uint4* __restrict__ bfrag2,
    ushort* __restrict__ mlpb)
{
    __shared__ __align__(16) ushort hbuf[4][16 * HSTRIDE];  // per-wave h (17,408 B)
    __shared__ float hisbuf[128];
    __shared__ __align__(4) ushort tbuf[4][8 * 16];

    int i = blockIdx.x, b = blockIdx.y;
    int t = threadIdx.x;
    int wave = t >> 6, lane = t & 63;
    int l15 = lane & 15, qd = lane >> 4;

    // in-block his: hisbuf[c] = b1[c] + feat_i . W1a  (c<64: s-set, else o-set)
    if (t < 128) {
        int set = t >> 6, kk = t & 63;
        const float* W1 = set ? foW1 : fsW1;
        const float* fi = (set ? of : sf) + (b * N_ + i) * FEAT_;
        float a = (set ? fob1 : fsb1)[kk];
        #pragma unroll
        for (int f = 0; f < FEAT_; f++) a += fi[f] * W1[f * 64 + kk];
        hisbuf[t] = a;
    }

    // B-fragments: coalesced global loads in frag order (L2-resident)
    bf16x8 Bf1[8], Bf2[4];
    #pragma unroll
    for (int nt = 0; nt < 8; nt++) { U8 u; u.u = bfrag1[nt * 64 + lane]; Bf1[nt] = u.h; }
    #pragma unroll
    for (int ks = 0; ks < 4; ks++) { U8 u; u.u = bfrag2[ks * 64 + lane]; Bf2[ks] = u.h; }

    const float* fsr = sf + (b * N_ + i) * FEAT_;
    const float* forr = of + (b * N_ + i) * FEAT_;
    float fsi[8], foi[8];
    #pragma unroll
    for (int u = 0; u < 8; u++) { fsi[u] = fsr[u]; foi[u] = forr[u]; }
    float b2l = LAM_ * (fsb2[l15 & 7] + fob2[l15 & 7]);

    __syncthreads();   // hisbuf ready (cross-wave)

    float hv[8];
    #pragma unroll
    for (int nt = 0; nt < 8; nt++) hv[nt] = hisbuf[nt * 16 + l15];

    ushort* hb = hbuf[wave];
    #pragma unroll
    for (int qt = 0; qt < 4; qt++) {
        int j0 = (wave * 4 + qt) * 16;
        int j = j0 + l15;

        // ---- A-frag: qd0 |ds|, qd1 fs_j, qd2 |do|, qd3 fo_j ----
        const float* fr = ((qd < 2) ? sf : of) + (b * N_ + j) * FEAT_;
        float4 f0 = *(const float4*)&fr[0];
        float4 f1 = *(const float4*)&fr[4];
        float vals[8] = {f0.x, f0.y, f0.z, f0.w, f1.x, f1.y, f1.z, f1.w};
        if ((qd & 1) == 0) {
            const float* fi = (qd < 2) ? fsi : foi;
            #pragma unroll
            for (int u = 0; u < 8; u++) vals[u] = fabsf(vals[u] - fi[u]);
        }
        U8 au;
        #pragma unroll
        for (int p = 0; p < 4; p++)
            ((uint32_t*)&au)[p] = pk_bf16(vals[2 * p], vals[2 * p + 1]);
        bf16x8 af = au.h;

        // ---- GEMM1 with his in C-operand ----
        f32x4 S1[8];
        #pragma unroll
        for (int nt = 0; nt < 8; nt++) {
            f32x4 c0 = {hv[nt], hv[nt], hv[nt], hv[nt]};
            S1[nt] = __builtin_amdgcn_mfma_f32_16x16x32_bf16(af, Bf1[nt], c0, 0, 0, 0);
        }

        // ---- relu + packed cvt + one b128 write per row (pi layout) ----
        #pragma unroll
        for (int r = 0; r < 4; r++) {
            uint4 w;
            w.x = pk_bf16(fmaxf(S1[0][r], 0.f), fmaxf(S1[1][r], 0.f));
            w.y = pk_bf16(fmaxf(S1[2][r], 0.f), fmaxf(S1[3][r], 0.f));
            w.z = pk_bf16(fmaxf(S1[4][r], 0.f), fmaxf(S1[5][r], 0.f));
            w.w = pk_bf16(fmaxf(S1[6][r], 0.f), fmaxf(S1[7][r], 0.f));
            *(uint4*)&hb[(qd * 4 + r) * HSTRIDE + l15 * 8] = w;
        }
        LDS_FENCE();   // LDS-only: h writes ordered before GEMM2 reads

        // ---- GEMM2: K=128 (pi-consistent), C-init = LAM*b2 ----
        f32x4 S2 = {b2l, b2l, b2l, b2l};
        #pragma unroll
        for (int ks = 0; ks < 4; ks++) {
            bf16x8 a2 = *(const bf16x8*)&hb[l15 * HSTRIDE + ks * 32 + qd * 8];
            S2 = __builtin_amdgcn_mfma_f32_16x16x32_bf16(a2, Bf2[ks], S2, 0, 0, 0);
        }

        // ---- transpose 16j x 8h via tbuf (per-wave) ----
        if (l15 < 8) {
            #pragma unroll
            for (int r = 0; r < 4; r++)
                tbuf[wave][l15 * 16 + qd * 4 + r] = f32_to_bf16(S2[r]);
        }
        LDS_FENCE();   // LDS-only: tbuf writes ordered before reads

        {
            int h2 = lane >> 3, jp = lane & 7;
            uint32_t lo = tbuf[wave][h2 * 16 + jp * 2];
            uint32_t hi = tbuf[wave][h2 * 16 + jp * 2 + 1];
            uint32_t pk = lo | (hi << 16);
            *(uint32_t*)&mlpb[(((size_t)(b * H_ + h2) * N_ + i) * N_) + j0 + jp * 2] = pk;
        }
    }
}

// ---------- K4: MFMA attention (ctx bf16) (unchanged) ----------
__global__ __launch_bounds__(256, 2) void attn_kernel(
    const ushort* __restrict__ qh, const ushort* __restrict__ kh,
    const ushort* __restrict__ vh, const float* __restrict__ tree,
    const ushort* __restrict__ mlpb, ushort* __restrict__ ctxb)
{
    __shared__ __align__(16) ushort bufKP[256 * 72];
    __shared__ __align__(16) ushort bufV[64 * 264];

    int blk = blockIdx.x;
    int bh = blk >> 2;
    int quarter = blk & 3;

    int t = threadIdx.x;
    int wave = t >> 6, lane = t & 63;
    int l15 = lane & 15, qd = lane >> 4;
    int i0w = quarter * 64 + wave * 16;

    const ushort* khb = kh + (size_t)bh * N_ * DK_;
    const ushort* vhb = vh + (size_t)bh * N_ * DK_;

    #pragma unroll
    for (int u = t; u < 2048; u += 256) {
        int j = u >> 3, seg = (u & 7) * 8;
        uint4 kv = *(const uint4*)&khb[j * DK_ + seg];
        *(uint4*)&bufKP[j * 72 + seg] = kv;
    }
    #pragma unroll
    for (int u = t; u < 1024; u += 256) {
        int rp = u & 127, d0 = (u >> 7) * 8;
        U8 v0, v1;
        v0.u = *(const uint4*)&vhb[(2 * rp) * DK_ + d0];
        v1.u = *(const uint4*)&vhb[(2 * rp + 1) * DK_ + d0];
        #pragma unroll
        for (int jj = 0; jj < 8; jj++) {
            uint32_t pk = (uint32_t)v0.s[jj] | ((uint32_t)v1.s[jj] << 16);
            *(uint32_t*)&bufV[(d0 + jj) * 264 + 2 * rp] = pk;
        }
    }
    __syncthreads();

    bf16x8 a0, a1;
    {
        size_t qb = ((size_t)bh * N_ + i0w + l15) * DK_;
        U8 t0, t1;
        t0.u = *(const uint4*)&qh[qb + qd * 8];
        t1.u = *(const uint4*)&qh[qb + 32 + qd * 8];
        a0 = t0.h; a1 = t1.h;
    }
    f32x4 S[16];
    #pragma unroll
    for (int nt = 0; nt < 16; nt++) {
        f32x4 acc = {};
        bf16x8 b0 = *(const bf16x8*)&bufKP[(nt * 16 + l15) * 72 + qd * 8];
        bf16x8 b1 = *(const bf16x8*)&bufKP[(nt * 16 + l15) * 72 + 32 + qd * 8];
        acc = __builtin_amdgcn_mfma_f32_16x16x32_bf16(a0, b0, acc, 0, 0, 0);
        acc = __builtin_amdgcn_mfma_f32_16x16x32_bf16(a1, b1, acc, 0, 0, 0);
        S[nt] = acc;
    }

    {
        size_t base = ((size_t)bh * N_ + i0w + qd * 4) * N_ + l15;
        const float*  tr = tree + base;
        const ushort* mb = mlpb + base;
        #pragma unroll
        for (int nt = 0; nt < 16; nt++)
            #pragma unroll
            for (int r = 0; r < 4; r++)
                S[nt][r] += tr[(size_t)r * N_ + nt * 16] + bf16_to_f32(mb[(size_t)r * N_ + nt * 16]);
    }

    float mx[4], sm[4];
    #pragma unroll
    for (int r = 0; r < 4; r++) mx[r] = -1e30f;
    #pragma unroll
    for (int nt = 0; nt < 16; nt++)
        #pragma unroll
        for (int r = 0; r < 4; r++) mx[r] = fmaxf(mx[r], S[nt][r]);
    #pragma unroll
    for (int r = 0; r < 4; r++) {
        #pragma unroll
        for (int m = 1; m <= 8; m <<= 1) mx[r] = fmaxf(mx[r], __shfl_xor(mx[r], m));
    }
    #pragma unroll
    for (int r = 0; r < 4; r++) sm[r] = 0.f;
    #pragma unroll
    for (int nt = 0; nt < 16; nt++)
        #pragma unroll
        for (int r = 0; r < 4; r++) {
            float e = __expf(S[nt][r] - mx[r]);
            S[nt][r] = e;
            sm[r] += e;
        }
    #pragma unroll
    for (int r = 0; r < 4; r++) {
        #pragma unroll
        for (int m = 1; m <= 8; m <<= 1) sm[r] += __shfl_xor(sm[r], m);
        sm[r] = 1.0f / sm[r];
    }

    __syncthreads();

    {
        uint32_t* Pw = (uint32_t*)&bufKP[wave * 16 * 264];
        #pragma unroll
        for (int nt = 0; nt < 16; nt++)
            #pragma unroll
            for (int r = 0; r < 4; r++) {
                float p = S[nt][r] * sm[r];
                float po = __shfl_xor(p, 1);
                uint32_t pk = (uint32_t)f32_to_bf16(p) | ((uint32_t)f32_to_bf16(po) << 16);
                if ((lane & 1) == 0)
                    Pw[(qd * 4 + r) * 132 + nt * 8 + (l15 >> 1)] = pk;
            }
    }
    __syncthreads();   // P writes complete before PV reads

    const ushort* Pw = &bufKP[wave * 16 * 264];
    f32x4 O[4] = {};
    #pragma unroll
    for (int ks = 0; ks < 8; ks++) {
        int j0 = ks * 32;
        bf16x8 pa = *(const bf16x8*)&Pw[l15 * 264 + j0 + qd * 8];
        #pragma unroll
        for (int ntd = 0; ntd < 4; ntd++) {
            bf16x8 vb = *(const bf16x8*)&bufV[(ntd * 16 + l15) * 264 + j0 + qd * 8];
            O[ntd] = __builtin_amdgcn_mfma_f32_16x16x32_bf16(pa, vb, O[ntd], 0, 0, 0);
        }
    }

    #pragma unroll
    for (int ntd = 0; ntd < 4; ntd++)
        #pragma unroll
        for (int r = 0; r < 4; r++)
            ctxb[((size_t)bh * N_ + i0w + qd * 4 + r) * DK_ + ntd * 16 + l15] =
                f32_to_bf16(O[ntd][r]);
}

// ---------- K5: output projection, bf16 MFMA (unchanged) ----------
__global__ __launch_bounds__(256, 4) void outproj_kernel(
    const ushort* __restrict__ ctxb, const float* __restrict__ Wo,
    const float* __restrict__ bo, float* __restrict__ out)
{
    int m0 = blockIdx.x * 64;
    int c0 = blockIdx.y * 64;

    __shared__ __align__(16) ushort Xs[64 * 40];
    __shared__ __align__(16) ushort Ws[64 * 40];

    int t = threadIdx.x;
    int wave = t >> 6, lane = t & 63;
    int l15 = lane & 15, qd = lane >> 4;

    f32x4 acc[4] = {};

    for (int k0 = 0; k0 < HID_; k0 += 32) {
        __syncthreads();
        {
            int r = t >> 2, s8 = (t & 3) * 8;
            int m = m0 + r, b_ = m >> 8, n_ = m & 255;
            uint4 xv = *(const uint4*)&ctxb[(((b_ * H_ + (k0 >> 6)) * N_) + n_) * DK_ + (k0 & 63) + s8];
            *(uint4*)&Xs[r * 40 + s8] = xv;
        }
        {
            int kr = t & 15, nq = t >> 4;
            float4 w0 = *(const float4*)&Wo[(k0 + 2 * kr) * HID_ + c0 + nq * 4];
            float4 w1 = *(const float4*)&Wo[(k0 + 2 * kr + 1) * HID_ + c0 + nq * 4];
            const float* a0 = &w0.x; const float* a1 = &w1.x;
            #pragma unroll
            for (int i = 0; i < 4; i++) {
                uint32_t pk = (uint32_t)f32_to_bf16(a0[i]) | ((uint32_t)f32_to_bf16(a1[i]) << 16);
                *(uint32_t*)&Ws[(nq * 4 + i) * 40 + 2 * kr] = pk;
            }
        }
        __syncthreads();
        bf16x8 af = *(const bf16x8*)&Xs[(wave * 16 + l15) * 40 + qd * 8];
        #pragma unroll
        for (int nt = 0; nt < 4; nt++) {
            bf16x8 bf = *(const bf16x8*)&Ws[(nt * 16 + l15) * 40 + qd * 8];
            acc[nt] = __builtin_amdgcn_mfma_f32_16x16x32_bf16(af, bf, acc[nt], 0, 0, 0);
        }
    }

    #pragma unroll
    for (int nt = 0; nt < 4; nt++) {
        float bb = bo[c0 + nt * 16 + l15];
        #pragma unroll
        for (int r = 0; r < 4; r++) {
            int m = m0 + wave * 16 + qd * 4 + r;
            out[m * HID_ + c0 + nt * 16 + l15] = acc[nt][r] + bb;
        }
    }
}

// ---------- launch ----------
extern "C" void kernel_launch(void* const* d_in, const int* in_sizes, int n_in,
                              void* d_out, int out_size, void* d_ws, size_t ws_size,
                              hipStream_t stream)
{
    const float* q    = (const float*)d_in[0];
    const float* k    = (const float*)d_in[1];
    const float* v    = (const float*)d_in[2];
    const float* tree = (const float*)d_in[3];
    const float* sf   = (const float*)d_in[4];
    const float* of   = (const float*)d_in[5];
    const float* Wq   = (const float*)d_in[6];
    const float* bq   = (const float*)d_in[7];
    const float* Wk   = (const float*)d_in[8];
    const float* bk   = (const float*)d_in[9];
    const float* Wv   = (const float*)d_in[10];
    const float* bv   = (const float*)d_in[11];
    const float* Wo   = (const float*)d_in[12];
    const float* bo   = (const float*)d_in[13];
    const float* fsW1 = (const float*)d_in[14];
    const float* fsb1 = (const float*)d_in[15];
    const float* fsW2 = (const float*)d_in[16];
    const float* fsb2 = (const float*)d_in[17];
    const float* foW1 = (const float*)d_in[18];
    const float* fob1 = (const float*)d_in[19];
    const float* foW2 = (const float*)d_in[20];
    const float* fob2 = (const float*)d_in[21];

    char* ws = (char*)d_ws;
    ushort* qh     = (ushort*)(ws + 0);            // 4,194,304
    ushort* kh     = (ushort*)(ws + 4194304);      // 4,194,304
    ushort* vh     = (ushort*)(ws + 8388608);      // 4,194,304
    ushort* ctxb   = (ushort*)(ws + 12582912);     // 4,194,304 (bf16)
    uint4*  bfrag1 = (uint4*)(ws + 16777216);      //     8,192
    uint4*  bfrag2 = (uint4*)(ws + 16785408);      //     4,096
    ushort* mlpb   = (ushort*)(ws + 23080960);     // 16,777,216

    proj_kernel<<<dim3(64, 8, 3), 256, 0, stream>>>(q, k, v, Wq, bq, Wk, bk, Wv, bv, qh, kh, vh);
    prep_frags<<<1, 256, 0, stream>>>(fsW1, foW1, fsW2, foW2, bfrag1, bfrag2);
    pair_bias_mfma<<<dim3(N_, B_), 256, 0, stream>>>(sf, of, fsW1, fsb1, foW1, fob1,
                                                     fsb2, fob2, bfrag1, bfrag2, mlpb);
    attn_kernel<<<512, 256, 0, stream>>>(qh, kh, vh, tree, mlpb, ctxb);
    outproj_kernel<<<dim3(64, 8), 256, 0, stream>>>(ctxb, Wo, bo, (float*)d_out);
}

// Round 11
// 228.081 us; speedup vs baseline: 1.7300x; 1.0257x over previous
//
#include <hip/hip_runtime.h>
#include <hip/hip_bf16.h>
#include <stdint.h>

// Problem constants
#define B_    16
#define N_    256
#define HID_  512
#define H_    8
#define DK_   64
#define FEAT_ 8
#define MLPH_ 64
#define LAM_  0.1f
#define SCALE_ 0.125f   // DK^-0.5

typedef short bf16x8 __attribute__((ext_vector_type(8)));
typedef float f32x4  __attribute__((ext_vector_type(4)));

union U8 { uint4 u; bf16x8 h; ushort s[8]; };

__device__ __forceinline__ uint16_t f32_to_bf16(float x) {
    uint32_t u = __float_as_uint(x);
    u += 0x7fffu + ((u >> 16) & 1u);      // RNE (no NaN/Inf in this data)
    return (uint16_t)(u >> 16);
}
__device__ __forceinline__ float bf16_to_f32(uint16_t v) {
    return __uint_as_float(((uint32_t)v) << 16);
}
__device__ __forceinline__ uint32_t pk_bf16(float lo, float hi) {
    float2 xy; xy.x = lo; xy.y = hi;
    __hip_bfloat162 b2 = __float22bfloat162_rn(xy);   // HW packed cvt on gfx950
    return *(uint32_t*)&b2;                            // .x in low 16 bits
}
// LDS-only fence: compiler barrier + drain LDS queue (no vmcnt wait).
#define LDS_FENCE() asm volatile("s_waitcnt lgkmcnt(0)" ::: "memory")

// ---------- K1: QKV projection, bf16 MFMA GEMM ----------
// R11: M=128 tile, double-buffered LDS, register prefetch, ONE barrier/iter.
// Old structure: 16 iters x 2 barriers x 4 MFMA/wave -> latency-bound (45 us,
// MfmaUtil 5%). New: 8 MFMA/wave per barrier, tile-k+1 loads in flight across
// the MFMA section. grid (32, 8, 3).
__global__ __launch_bounds__(256, 4) void proj_kernel(
    const float* __restrict__ q, const float* __restrict__ k, const float* __restrict__ v,
    const float* __restrict__ Wq, const float* __restrict__ bq,
    const float* __restrict__ Wk, const float* __restrict__ bk,
    const float* __restrict__ Wv, const float* __restrict__ bv,
    ushort* __restrict__ qh, ushort* __restrict__ kh, ushort* __restrict__ vh)
{
    int z = blockIdx.z;
    const float* X    = (z == 0) ? q  : (z == 1) ? k  : v;
    const float* W    = (z == 0) ? Wq : (z == 1) ? Wk : Wv;
    const float* bias = (z == 0) ? bq : (z == 1) ? bk : bv;
    ushort* out       = (z == 0) ? qh : (z == 1) ? kh : vh;
    float scale       = (z == 0) ? SCALE_ : 1.0f;

    int m0 = blockIdx.x * 128;
    int h  = blockIdx.y;
    int c0 = h * 64;

    __shared__ __align__(16) ushort Xs[2][128 * 40];
    __shared__ __align__(16) ushort Ws[2][64 * 40];

    int t = threadIdx.x;
    int wave = t >> 6, lane = t & 63;
    int l15 = lane & 15, qd = lane >> 4;

    // loader mapping
    int xr = t >> 1, xc = (t & 1) * 16;   // X: row 0..127, k-half 0/16
    int kr = t & 15, nq = t >> 4;         // W: k-pair 0..15, n-quad 0..15

    f32x4 acc0[4] = {}, acc1[4] = {};

    // prologue: prefetch tile 0
    float4 xv[4], w0, w1;
    #pragma unroll
    for (int p = 0; p < 4; p++)
        xv[p] = *(const float4*)&X[(m0 + xr) * HID_ + xc + p * 4];
    w0 = *(const float4*)&W[(2 * kr) * HID_ + c0 + nq * 4];
    w1 = *(const float4*)&W[(2 * kr + 1) * HID_ + c0 + nq * 4];

    for (int k0 = 0; k0 < HID_; k0 += 32) {
        int buf = (k0 >> 5) & 1;
        // write prefetched regs -> LDS[buf]
        #pragma unroll
        for (int p = 0; p < 4; p++) {
            ushort4 o;
            o.x = f32_to_bf16(xv[p].x); o.y = f32_to_bf16(xv[p].y);
            o.z = f32_to_bf16(xv[p].z); o.w = f32_to_bf16(xv[p].w);
            *(ushort4*)&Xs[buf][xr * 40 + xc + p * 4] = o;
        }
        {
            const float* a0 = &w0.x; const float* a1 = &w1.x;
            #pragma unroll
            for (int i = 0; i < 4; i++) {
                uint32_t pk = (uint32_t)f32_to_bf16(a0[i]) | ((uint32_t)f32_to_bf16(a1[i]) << 16);
                *(uint32_t*)&Ws[buf][(nq * 4 + i) * 40 + 2 * kr] = pk;
            }
        }
        __syncthreads();   // single barrier: buf written; prior-iter reads of buf^1 done

        // issue tile k+1 loads (overlap with MFMA below)
        if (k0 + 32 < HID_) {
            int kn = k0 + 32;
            #pragma unroll
            for (int p = 0; p < 4; p++)
                xv[p] = *(const float4*)&X[(m0 + xr) * HID_ + kn + xc + p * 4];
            w0 = *(const float4*)&W[(kn + 2 * kr) * HID_ + c0 + nq * 4];
            w1 = *(const float4*)&W[(kn + 2 * kr + 1) * HID_ + c0 + nq * 4];
        }

        // MFMA: wave owns rows wave*32 .. +31 (two 16-row groups)
        bf16x8 af0 = *(const bf16x8*)&Xs[buf][(wave * 32 + l15) * 40 + qd * 8];
        bf16x8 af1 = *(const bf16x8*)&Xs[buf][(wave * 32 + 16 + l15) * 40 + qd * 8];
        #pragma unroll
        for (int nt = 0; nt < 4; nt++) {
            bf16x8 bf = *(const bf16x8*)&Ws[buf][(nt * 16 + l15) * 40 + qd * 8];
            acc0[nt] = __builtin_amdgcn_mfma_f32_16x16x32_bf16(af0, bf, acc0[nt], 0, 0, 0);
            acc1[nt] = __builtin_amdgcn_mfma_f32_16x16x32_bf16(af1, bf, acc1[nt], 0, 0, 0);
        }
    }

    // epilogue: bias + scale, bf16 store in head layout
    #pragma unroll
    for (int nt = 0; nt < 4; nt++) {
        float bb = bias[c0 + nt * 16 + l15];
        #pragma unroll
        for (int g = 0; g < 2; g++) {
            const f32x4& a = g ? acc1[nt] : acc0[nt];
            #pragma unroll
            for (int r = 0; r < 4; r++) {
                int m = m0 + wave * 32 + g * 16 + qd * 4 + r;
                int b_ = m >> 8, n_ = m & 255;
                float val = (a[r] + bb) * scale;
                out[(((b_ * H_ + h) * N_) + n_) * DK_ + nt * 16 + l15] = f32_to_bf16(val);
            }
        }
    }
}

// ---------- K2: one-block prep — B-fragments in MFMA frag order (unchanged) ----
__global__ void prep_frags(const float* __restrict__ fsW1, const float* __restrict__ foW1,
                           const float* __restrict__ fsW2, const float* __restrict__ foW2,
                           uint4* __restrict__ bfrag1, uint4* __restrict__ bfrag2)
{
    int t = threadIdx.x;
    #pragma unroll
    for (int e = t; e < 512; e += 256) {
        int nt = e >> 6, lane = e & 63, l15 = lane & 15, qd = lane >> 4;
        int n = nt * 16 + l15;
        ushort vals[8];
        #pragma unroll
        for (int u = 0; u < 8; u++) {
            float x = 0.f;
            if (n < 64) {
                if (qd == 0) x = fsW1[(16 + u) * 64 + n];
                else if (qd == 1) x = fsW1[(8 + u) * 64 + n];
            } else {
                int n2 = n - 64;
                if (qd == 2) x = foW1[(16 + u) * 64 + n2];
                else if (qd == 3) x = foW1[(8 + u) * 64 + n2];
            }
            vals[u] = f32_to_bf16(x);
        }
        uint4 pk;
        pk.x = (uint32_t)vals[0] | ((uint32_t)vals[1] << 16);
        pk.y = (uint32_t)vals[2] | ((uint32_t)vals[3] << 16);
        pk.z = (uint32_t)vals[4] | ((uint32_t)vals[5] << 16);
        pk.w = (uint32_t)vals[6] | ((uint32_t)vals[7] << 16);
        bfrag1[e] = pk;
    }
    {
        int e = t;
        int ks = e >> 6, lane = e & 63, l15 = lane & 15, qd = lane >> 4;
        ushort vals[8];
        #pragma unroll
        for (int u = 0; u < 8; u++) {
            float x = 0.f;
            if (l15 < 8) {
                int k2 = ks * 32 + qd * 8 + u;
                int c = ((k2 & 7) << 4) | (k2 >> 3);
                x = LAM_ * ((c < 64) ? fsW2[c * 8 + l15] : foW2[(c - 64) * 8 + l15]);
            }
            vals[u] = f32_to_bf16(x);
        }
        uint4 pk;
        pk.x = (uint32_t)vals[0] | ((uint32_t)vals[1] << 16);
        pk.y = (uint32_t)vals[2] | ((uint32_t)vals[3] << 16);
        pk.z = (uint32_t)vals[4] | ((uint32_t)vals[5] << 16);
        pk.w = (uint32_t)vals[6] | ((uint32_t)vals[7] << 16);
        bfrag2[e] = pk;
    }
}

// ---------- K3: pair-MLP via MFMA (unchanged from R10) ----------
#define HSTRIDE 136
__global__ __launch_bounds__(256, 4) void pair_bias_mfma(
    const float* __restrict__ sf, const float* __restrict__ of,
    const float* __restrict__ fsW1, const float* __restrict__ fsb1,
    const float* __restrict__ foW1, const float* __restrict__ fob1,
    const float* __restrict__ fsb2, const float* __restrict__ fob2,
    const uint4* __restrict__ bfrag1, const uint4* __restrict__ bfrag2,
    ushort* __restrict__ mlpb)
{
    __shared__ __align__(16) ushort hbuf[4][16 * HSTRIDE];
    __shared__ float hisbuf[128];
    __shared__ __align__(4) ushort tbuf[4][8 * 16];

    int i = blockIdx.x, b = blockIdx.y;
    int t = threadIdx.x;
    int wave = t >> 6, lane = t & 63;
    int l15 = lane & 15, qd = lane >> 4;

    if (t < 128) {
        int set = t >> 6, kk = t & 63;
        const float* W1 = set ? foW1 : fsW1;
        const float* fi = (set ? of : sf) + (b * N_ + i) * FEAT_;
        float a = (set ? fob1 : fsb1)[kk];
        #pragma unroll
        for (int f = 0; f < FEAT_; f++) a += fi[f] * W1[f * 64 + kk];
        hisbuf[t] = a;
    }

    bf16x8 Bf1[8], Bf2[4];
    #pragma unroll
    for (int nt = 0; nt < 8; nt++) { U8 u; u.u = bfrag1[nt * 64 + lane]; Bf1[nt] = u.h; }
    #pragma unroll
    for (int ks = 0; ks < 4; ks++) { U8 u; u.u = bfrag2[ks * 64 + lane]; Bf2[ks] = u.h; }

    const float* fsr = sf + (b * N_ + i) * FEAT_;
    const float* forr = of + (b * N_ + i) * FEAT_;
    float fsi[8], foi[8];
    #pragma unroll
    for (int u = 0; u < 8; u++) { fsi[u] = fsr[u]; foi[u] = forr[u]; }
    float b2l = LAM_ * (fsb2[l15 & 7] + fob2[l15 & 7]);

    __syncthreads();   // hisbuf ready

    float hv[8];
    #pragma unroll
    for (int nt = 0; nt < 8; nt++) hv[nt] = hisbuf[nt * 16 + l15];

    ushort* hb = hbuf[wave];
    #pragma unroll
    for (int qt = 0; qt < 4; qt++) {
        int j0 = (wave * 4 + qt) * 16;
        int j = j0 + l15;

        const float* fr = ((qd < 2) ? sf : of) + (b * N_ + j) * FEAT_;
        float4 f0 = *(const float4*)&fr[0];
        float4 f1 = *(const float4*)&fr[4];
        float vals[8] = {f0.x, f0.y, f0.z, f0.w, f1.x, f1.y, f1.z, f1.w};
        if ((qd & 1) == 0) {
            const float* fi = (qd < 2) ? fsi : foi;
            #pragma unroll
            for (int u = 0; u < 8; u++) vals[u] = fabsf(vals[u] - fi[u]);
        }
        U8 au;
        #pragma unroll
        for (int p = 0; p < 4; p++)
            ((uint32_t*)&au)[p] = pk_bf16(vals[2 * p], vals[2 * p + 1]);
        bf16x8 af = au.h;

        f32x4 S1[8];
        #pragma unroll
        for (int nt = 0; nt < 8; nt++) {
            f32x4 c0 = {hv[nt], hv[nt], hv[nt], hv[nt]};
            S1[nt] = __builtin_amdgcn_mfma_f32_16x16x32_bf16(af, Bf1[nt], c0, 0, 0, 0);
        }

        #pragma unroll
        for (int r = 0; r < 4; r++) {
            uint4 w;
            w.x = pk_bf16(fmaxf(S1[0][r], 0.f), fmaxf(S1[1][r], 0.f));
            w.y = pk_bf16(fmaxf(S1[2][r], 0.f), fmaxf(S1[3][r], 0.f));
            w.z = pk_bf16(fmaxf(S1[4][r], 0.f), fmaxf(S1[5][r], 0.f));
            w.w = pk_bf16(fmaxf(S1[6][r], 0.f), fmaxf(S1[7][r], 0.f));
            *(uint4*)&hb[(qd * 4 + r) * HSTRIDE + l15 * 8] = w;
        }
        LDS_FENCE();

        f32x4 S2 = {b2l, b2l, b2l, b2l};
        #pragma unroll
        for (int ks = 0; ks < 4; ks++) {
            bf16x8 a2 = *(const bf16x8*)&hb[l15 * HSTRIDE + ks * 32 + qd * 8];
            S2 = __builtin_amdgcn_mfma_f32_16x16x32_bf16(a2, Bf2[ks], S2, 0, 0, 0);
        }

        if (l15 < 8) {
            #pragma unroll
            for (int r = 0; r < 4; r++)
                tbuf[wave][l15 * 16 + qd * 4 + r] = f32_to_bf16(S2[r]);
        }
        LDS_FENCE();

        {
            int h2 = lane >> 3, jp = lane & 7;
            uint32_t lo = tbuf[wave][h2 * 16 + jp * 2];
            uint32_t hi = tbuf[wave][h2 * 16 + jp * 2 + 1];
            uint32_t pk = lo | (hi << 16);
            *(uint32_t*)&mlpb[(((size_t)(b * H_ + h2) * N_ + i) * N_) + j0 + jp * 2] = pk;
        }
    }
}

// ---------- K4: MFMA attention (unchanged) ----------
__global__ __launch_bounds__(256, 2) void attn_kernel(
    const ushort* __restrict__ qh, const ushort* __restrict__ kh,
    const ushort* __restrict__ vh, const float* __restrict__ tree,
    const ushort* __restrict__ mlpb, ushort* __restrict__ ctxb)
{
    __shared__ __align__(16) ushort bufKP[256 * 72];
    __shared__ __align__(16) ushort bufV[64 * 264];

    int blk = blockIdx.x;
    int bh = blk >> 2;
    int quarter = blk & 3;

    int t = threadIdx.x;
    int wave = t >> 6, lane = t & 63;
    int l15 = lane & 15, qd = lane >> 4;
    int i0w = quarter * 64 + wave * 16;

    const ushort* khb = kh + (size_t)bh * N_ * DK_;
    const ushort* vhb = vh + (size_t)bh * N_ * DK_;

    #pragma unroll
    for (int u = t; u < 2048; u += 256) {
        int j = u >> 3, seg = (u & 7) * 8;
        uint4 kv = *(const uint4*)&khb[j * DK_ + seg];
        *(uint4*)&bufKP[j * 72 + seg] = kv;
    }
    #pragma unroll
    for (int u = t; u < 1024; u += 256) {
        int rp = u & 127, d0 = (u >> 7) * 8;
        U8 v0, v1;
        v0.u = *(const uint4*)&vhb[(2 * rp) * DK_ + d0];
        v1.u = *(const uint4*)&vhb[(2 * rp + 1) * DK_ + d0];
        #pragma unroll
        for (int jj = 0; jj < 8; jj++) {
            uint32_t pk = (uint32_t)v0.s[jj] | ((uint32_t)v1.s[jj] << 16);
            *(uint32_t*)&bufV[(d0 + jj) * 264 + 2 * rp] = pk;
        }
    }
    __syncthreads();

    bf16x8 a0, a1;
    {
        size_t qb = ((size_t)bh * N_ + i0w + l15) * DK_;
        U8 t0, t1;
        t0.u = *(const uint4*)&qh[qb + qd * 8];
        t1.u = *(const uint4*)&qh[qb + 32 + qd * 8];
        a0 = t0.h; a1 = t1.h;
    }
    f32x4 S[16];
    #pragma unroll
    for (int nt = 0; nt < 16; nt++) {
        f32x4 acc = {};
        bf16x8 b0 = *(const bf16x8*)&bufKP[(nt * 16 + l15) * 72 + qd * 8];
        bf16x8 b1 = *(const bf16x8*)&bufKP[(nt * 16 + l15) * 72 + 32 + qd * 8];
        acc = __builtin_amdgcn_mfma_f32_16x16x32_bf16(a0, b0, acc, 0, 0, 0);
        acc = __builtin_amdgcn_mfma_f32_16x16x32_bf16(a1, b1, acc, 0, 0, 0);
        S[nt] = acc;
    }

    {
        size_t base = ((size_t)bh * N_ + i0w + qd * 4) * N_ + l15;
        const float*  tr = tree + base;
        const ushort* mb = mlpb + base;
        #pragma unroll
        for (int nt = 0; nt < 16; nt++)
            #pragma unroll
            for (int r = 0; r < 4; r++)
                S[nt][r] += tr[(size_t)r * N_ + nt * 16] + bf16_to_f32(mb[(size_t)r * N_ + nt * 16]);
    }

    float mx[4], sm[4];
    #pragma unroll
    for (int r = 0; r < 4; r++) mx[r] = -1e30f;
    #pragma unroll
    for (int nt = 0; nt < 16; nt++)
        #pragma unroll
        for (int r = 0; r < 4; r++) mx[r] = fmaxf(mx[r], S[nt][r]);
    #pragma unroll
    for (int r = 0; r < 4; r++) {
        #pragma unroll
        for (int m = 1; m <= 8; m <<= 1) mx[r] = fmaxf(mx[r], __shfl_xor(mx[r], m));
    }
    #pragma unroll
    for (int r = 0; r < 4; r++) sm[r] = 0.f;
    #pragma unroll
    for (int nt = 0; nt < 16; nt++)
        #pragma unroll
        for (int r = 0; r < 4; r++) {
            float e = __expf(S[nt][r] - mx[r]);
            S[nt][r] = e;
            sm[r] += e;
        }
    #pragma unroll
    for (int r = 0; r < 4; r++) {
        #pragma unroll
        for (int m = 1; m <= 8; m <<= 1) sm[r] += __shfl_xor(sm[r], m);
        sm[r] = 1.0f / sm[r];
    }

    __syncthreads();

    {
        uint32_t* Pw = (uint32_t*)&bufKP[wave * 16 * 264];
        #pragma unroll
        for (int nt = 0; nt < 16; nt++)
            #pragma unroll
            for (int r = 0; r < 4; r++) {
                float p = S[nt][r] * sm[r];
                float po = __shfl_xor(p, 1);
                uint32_t pk = (uint32_t)f32_to_bf16(p) | ((uint32_t)f32_to_bf16(po) << 16);
                if ((lane & 1) == 0)
                    Pw[(qd * 4 + r) * 132 + nt * 8 + (l15 >> 1)] = pk;
            }
    }
    __syncthreads();

    const ushort* Pw = &bufKP[wave * 16 * 264];
    f32x4 O[4] = {};
    #pragma unroll
    for (int ks = 0; ks < 8; ks++) {
        int j0 = ks * 32;
        bf16x8 pa = *(const bf16x8*)&Pw[l15 * 264 + j0 + qd * 8];
        #pragma unroll
        for (int ntd = 0; ntd < 4; ntd++) {
            bf16x8 vb = *(const bf16x8*)&bufV[(ntd * 16 + l15) * 264 + j0 + qd * 8];
            O[ntd] = __builtin_amdgcn_mfma_f32_16x16x32_bf16(pa, vb, O[ntd], 0, 0, 0);
        }
    }

    #pragma unroll
    for (int ntd = 0; ntd < 4; ntd++)
        #pragma unroll
        for (int r = 0; r < 4; r++)
            ctxb[((size_t)bh * N_ + i0w + qd * 4 + r) * DK_ + ntd * 16 + l15] =
                f32_to_bf16(O[ntd][r]);
}

// ---------- K5: output projection, bf16 MFMA (unchanged) ----------
__global__ __launch_bounds__(256, 4) void outproj_kernel(
    const ushort* __restrict__ ctxb, const float* __restrict__ Wo,
    const float* __restrict__ bo, float* __restrict__ out)
{
    int m0 = blockIdx.x * 64;
    int c0 = blockIdx.y * 64;

    __shared__ __align__(16) ushort Xs[64 * 40];
    __shared__ __align__(16) ushort Ws[64 * 40];

    int t = threadIdx.x;
    int wave = t >> 6, lane = t & 63;
    int l15 = lane & 15, qd = lane >> 4;

    f32x4 acc[4] = {};

    for (int k0 = 0; k0 < HID_; k0 += 32) {
        __syncthreads();
        {
            int r = t >> 2, s8 = (t & 3) * 8;
            int m = m0 + r, b_ = m >> 8, n_ = m & 255;
            uint4 xv = *(const uint4*)&ctxb[(((b_ * H_ + (k0 >> 6)) * N_) + n_) * DK_ + (k0 & 63) + s8];
            *(uint4*)&Xs[r * 40 + s8] = xv;
        }
        {
            int kr = t & 15, nq = t >> 4;
            float4 w0 = *(const float4*)&Wo[(k0 + 2 * kr) * HID_ + c0 + nq * 4];
            float4 w1 = *(const float4*)&Wo[(k0 + 2 * kr + 1) * HID_ + c0 + nq * 4];
            const float* a0 = &w0.x; const float* a1 = &w1.x;
            #pragma unroll
            for (int i = 0; i < 4; i++) {
                uint32_t pk = (uint32_t)f32_to_bf16(a0[i]) | ((uint32_t)f32_to_bf16(a1[i]) << 16);
                *(uint32_t*)&Ws[(nq * 4 + i) * 40 + 2 * kr] = pk;
            }
        }
        __syncthreads();
        bf16x8 af = *(const bf16x8*)&Xs[(wave * 16 + l15) * 40 + qd * 8];
        #pragma unroll
        for (int nt = 0; nt < 4; nt++) {
            bf16x8 bf = *(const bf16x8*)&Ws[(nt * 16 + l15) * 40 + qd * 8];
            acc[nt] = __builtin_amdgcn_mfma_f32_16x16x32_bf16(af, bf, acc[nt], 0, 0, 0);
        }
    }

    #pragma unroll
    for (int nt = 0; nt < 4; nt++) {
        float bb = bo[c0 + nt * 16 + l15];
        #pragma unroll
        for (int r = 0; r < 4; r++) {
            int m = m0 + wave * 16 + qd * 4 + r;
            out[m * HID_ + c0 + nt * 16 + l15] = acc[nt][r] + bb;
        }
    }
}

// ---------- launch ----------
extern "C" void kernel_launch(void* const* d_in, const int* in_sizes, int n_in,
                              void* d_out, int out_size, void* d_ws, size_t ws_size,
                              hipStream_t stream)
{
    const float* q    = (const float*)d_in[0];
    const float* k    = (const float*)d_in[1];
    const float* v    = (const float*)d_in[2];
    const float* tree = (const float*)d_in[3];
    const float* sf   = (const float*)d_in[4];
    const float* of   = (const float*)d_in[5];
    const float* Wq   = (const float*)d_in[6];
    const float* bq   = (const float*)d_in[7];
    const float* Wk   = (const float*)d_in[8];
    const float* bk   = (const float*)d_in[9];
    const float* Wv   = (const float*)d_in[10];
    const float* bv   = (const float*)d_in[11];
    const float* Wo   = (const float*)d_in[12];
    const float* bo   = (const float*)d_in[13];
    const float* fsW1 = (const float*)d_in[14];
    const float* fsb1 = (const float*)d_in[15];
    const float* fsW2 = (const float*)d_in[16];
    const float* fsb2 = (const float*)d_in[17];
    const float* foW1 = (const float*)d_in[18];
    const float* fob1 = (const float*)d_in[19];
    const float* foW2 = (const float*)d_in[20];
    const float* fob2 = (const float*)d_in[21];

    char* ws = (char*)d_ws;
    ushort* qh     = (ushort*)(ws + 0);            // 4,194,304
    ushort* kh     = (ushort*)(ws + 4194304);      // 4,194,304
    ushort* vh     = (ushort*)(ws + 8388608);      // 4,194,304
    ushort* ctxb   = (ushort*)(ws + 12582912);     // 4,194,304 (bf16)
    uint4*  bfrag1 = (uint4*)(ws + 16777216);      //     8,192
    uint4*  bfrag2 = (uint4*)(ws + 16785408);      //     4,096
    ushort* mlpb   = (ushort*)(ws + 23080960);     // 16,777,216

    proj_kernel<<<dim3(32, 8, 3), 256, 0, stream>>>(q, k, v, Wq, bq, Wk, bk, Wv, bv, qh, kh, vh);
    prep_frags<<<1, 256, 0, stream>>>(fsW1, foW1, fsW2, foW2, bfrag1, bfrag2);
    pair_bias_mfma<<<dim3(N_, B_), 256, 0, stream>>>(sf, of, fsW1, fsb1, foW1, fob1,
                                                     fsb2, fob2, bfrag1, bfrag2, mlpb);
    attn_kernel<<<512, 256, 0, stream>>>(qh, kh, vh, tree, mlpb, ctxb);
    outproj_kernel<<<dim3(64, 8), 256, 0, stream>>>(ctxb, Wo, bo, (float*)d_out);
}